// Round 4
// baseline (12996.719 us; speedup 1.0000x reference)
//
#include <hip/hip_runtime.h>
#include <cstdint>
#include <cstddef>
#include <math.h>

#define SEQ   2048
#define DIM   2048
#define NQKV  6144
#define NH    16
#define DH    128
#define ROWS  4096   /* b*n */

// ------------------------------------------------ rmsnorm (fp64, 1 wave/row)
__global__ __launch_bounds__(64) void rms_slow(
    const float* __restrict__ x, const float* __restrict__ g,
    float* __restrict__ xn) {
  int row = blockIdx.x, lane = threadIdx.x;
  const float* xr = x + (size_t)row * DIM;
  double ss = 0.0;
  for (int c = lane; c < DIM; c += 64) { double v = xr[c]; ss += v * v; }
  #pragma unroll
  for (int off = 32; off >= 1; off >>= 1) ss += __shfl_xor(ss, off);
  double nrm = sqrt(ss); if (nrm < 1e-12) nrm = 1e-12;
  double sc = 45.254833995939045 / nrm;   // sqrt(2048)/||x||
  float* dst = xn + (size_t)row * DIM;
  for (int c = lane; c < DIM; c += 64) dst[c] = (float)((double)xr[c] * sc * (double)g[c]);
}

// ------------------------------------- fp32-in / fp64-acc NN GEMM, 64x64 tile
__global__ __launch_bounds__(256) void gemm_slow(
    const float* __restrict__ A, const float* __restrict__ B,
    float* __restrict__ C, int M, int N, int K) {
  __shared__ float As[64][17];
  __shared__ float Bs[16][64];
  int bm = blockIdx.y * 64, bn = blockIdx.x * 64;
  int tid = threadIdx.x, tx = tid & 15, ty = tid >> 4;
  double acc[4][4] = {};
  for (int k0 = 0; k0 < K; k0 += 16) {
    #pragma unroll
    for (int e0 = 0; e0 < 1024; e0 += 256) {
      int e = e0 + tid;
      As[e >> 4][e & 15]  = A[(size_t)(bm + (e >> 4)) * K + k0 + (e & 15)];
      Bs[e >> 6][e & 63]  = B[(size_t)(k0 + (e >> 6)) * N + bn + (e & 63)];
    }
    __syncthreads();
    #pragma unroll
    for (int kk = 0; kk < 16; ++kk)
      #pragma unroll
      for (int i = 0; i < 4; ++i)
        #pragma unroll
        for (int j = 0; j < 4; ++j)
          acc[i][j] += (double)As[ty * 4 + i][kk] * (double)Bs[kk][tx * 4 + j];
    __syncthreads();
  }
  #pragma unroll
  for (int i = 0; i < 4; ++i)
    #pragma unroll
    for (int j = 0; j < 4; ++j)
      C[(size_t)(bm + ty * 4 + i) * N + bn + tx * 4 + j] = (float)acc[i][j];
}

// ---------------------------------- cached_kv: one thread per output element
__global__ __launch_bounds__(256) void kvout_slow(
    const float* __restrict__ qkv, float* __restrict__ cached) {
  size_t gid = (size_t)blockIdx.x * 256 + threadIdx.x;  // 16,777,216
  int d = (int)(gid & 127);
  size_t r = gid >> 7;
  int n = (int)(r & 2047); r >>= 11;
  int h = (int)(r & 15);   r >>= 4;
  int b = (int)(r & 1);    r >>= 1;
  int kv = (int)r;         // 0=k, 1=v  (pre-RoPE)
  cached[gid] = qkv[(size_t)(b * SEQ + n) * NQKV + (size_t)(1 + kv) * DIM + h * DH + d];
}

// ------------------------------------------- RoPE in-place (fp64, per pair)
__global__ __launch_bounds__(256) void rope_slow(float* __restrict__ qkv) {
  int gid = blockIdx.x * 256 + threadIdx.x;   // 8,388,608 pairs (q and k)
  int p = gid & 63;
  int n = (gid >> 6) & 2047;
  int h = (gid >> 17) & 15;
  int s = (gid >> 21) & 1;    // 0 = q, 1 = k
  int b = (gid >> 22) & 1;
  float* base = qkv + (size_t)(b * SEQ + n) * NQKV + s * DIM + h * DH + 2 * p;
  double inv = pow(10000.0, -(double)p / 64.0);  // 10000^(-2p/128)
  double ang = (double)n * inv;
  double cs = cos(ang), sn = sin(ang);
  double t0 = base[0], t1 = base[1];
  base[0] = (float)(t0 * cs - t1 * sn);
  base[1] = (float)(t1 * cs + t0 * sn);
}

// --------------------- two-pass (non-flash) attention, fp64, 1 block per row
__global__ __launch_bounds__(256) void attn_slow(
    const float* __restrict__ qkv, float* __restrict__ ctx) {
  int i  = blockIdx.x & 2047;
  int bh = blockIdx.x >> 11;        // 0..31
  int b = bh >> 4, h = bh & 15;
  int tid = threadIdx.x;

  __shared__ float  qv[DH];
  __shared__ float  S[SEQ];
  __shared__ double red[256];

  const float* qrow  = qkv + (size_t)(b * SEQ + i) * NQKV + h * DH;
  const float* kbase = qkv + (size_t)(b * SEQ) * NQKV + DIM + h * DH;
  const float* vbase = qkv + (size_t)(b * SEQ) * NQKV + 2 * DIM + h * DH;

  if (tid < DH) qv[tid] = qrow[tid];
  __syncthreads();

  // pass 1: scores for j <= i
  for (int j = tid; j <= i; j += 256) {
    const float* kr = kbase + (size_t)j * NQKV;
    double s = 0.0;
    #pragma unroll 4
    for (int d = 0; d < DH; ++d) s += (double)qv[d] * (double)kr[d];
    S[j] = (float)(s * 0.08838834764831845);
  }
  __syncthreads();

  // row max
  float mx = -3.4e38f;
  for (int j = tid; j <= i; j += 256) mx = fmaxf(mx, S[j]);
  red[tid] = (double)mx;
  __syncthreads();
  for (int w = 128; w >= 1; w >>= 1) {
    if (tid < w) red[tid] = fmax(red[tid], red[tid + w]);
    __syncthreads();
  }
  double m = red[0];
  __syncthreads();

  // exp + denominator
  double ps = 0.0;
  for (int j = tid; j <= i; j += 256) {
    double p = exp((double)S[j] - m);
    S[j] = (float)p;
    ps += p;
  }
  red[tid] = ps;
  __syncthreads();
  for (int w = 128; w >= 1; w >>= 1) {
    if (tid < w) red[tid] += red[tid + w];
    __syncthreads();
  }
  double l = red[0];

  // pass 2: PV
  if (tid < DH) {
    double o = 0.0;
    #pragma unroll 4
    for (int j = 0; j <= i; ++j) o += (double)S[j] * (double)vbase[(size_t)j * NQKV + tid];
    ctx[(size_t)(b * SEQ + i) * DIM + h * DH + tid] = (float)(o / l);
  }
}

// ----------------------------------------------------------------- launch ---
extern "C" void kernel_launch(void* const* d_in, const int* in_sizes, int n_in,
                              void* d_out, int out_size, void* d_ws, size_t ws_size,
                              hipStream_t stream) {
  // size-keyed input selection (sizes are pairwise distinct)
  const float *x = nullptr, *gamma = nullptr, *wq = nullptr, *wo = nullptr;
  for (int ii = 0; ii < n_in; ++ii) {
    switch (in_sizes[ii]) {
      case  8388608: x     = (const float*)d_in[ii]; break;
      case     2048: gamma = (const float*)d_in[ii]; break;
      case 12582912: wq    = (const float*)d_in[ii]; break;
      case  4194304: wo    = (const float*)d_in[ii]; break;
    }
  }
  if (!x || !gamma || !wq || !wo) {   // fallback: documented dict order
    x = (const float*)d_in[0]; gamma = (const float*)d_in[1];
    wq = (const float*)d_in[2]; wo = (const float*)d_in[3];
  }

  float* out    = (float*)d_out;           // (2,2048,2048)
  float* cached = out + 8388608;           // (2,2,16,2048,128)

  // ws: [0,33.55MB) xn (reused as ctx after QKV GEMM) ; [33.55,134.2MB) qkv
  float* xn   = (float*)d_ws;
  float* ctx  = xn;
  float* qkvf = xn + (size_t)ROWS * DIM;

  rms_slow<<<ROWS, 64, 0, stream>>>(x, gamma, xn);
  gemm_slow<<<dim3(NQKV / 64, ROWS / 64), 256, 0, stream>>>(xn, wq, qkvf, ROWS, NQKV, DIM);
  kvout_slow<<<65536, 256, 0, stream>>>(qkvf, cached);
  rope_slow<<<32768, 256, 0, stream>>>(qkvf);
  attn_slow<<<65536, 256, 0, stream>>>(qkvf, ctx);
  gemm_slow<<<dim3(DIM / 64, ROWS / 64), 256, 0, stream>>>(ctx, wo, out, ROWS, DIM, DIM);
}

// Round 5
// 7479.953 us; speedup vs baseline: 1.7375x; 1.7375x over previous
//
#include <hip/hip_runtime.h>
#include <cstdint>
#include <cstddef>
#include <math.h>

#define SEQ   2048
#define DIM   2048
#define NQKV  6144
#define NH    16
#define DH    128
#define ROWS  4096   /* b*n */

typedef unsigned short u16;
typedef unsigned int u32;
typedef __attribute__((ext_vector_type(8))) short bf16x8;
typedef __attribute__((ext_vector_type(4))) float f32x4;

__device__ __forceinline__ u16 f2bf(float f) {
  union { float f; u32 u; } v;
  v.f = f;
  u32 r = v.u + 0x7FFFu + ((v.u >> 16) & 1u);
  return (u16)(r >> 16);
}

// ------------------------------------------------ rmsnorm (fp64, 1 wave/row)
// [VERIFIED round 4 — do not touch]
__global__ __launch_bounds__(64) void rms_slow(
    const float* __restrict__ x, const float* __restrict__ g,
    float* __restrict__ xn) {
  int row = blockIdx.x, lane = threadIdx.x;
  const float* xr = x + (size_t)row * DIM;
  double ss = 0.0;
  for (int c = lane; c < DIM; c += 64) { double v = xr[c]; ss += v * v; }
  #pragma unroll
  for (int off = 32; off >= 1; off >>= 1) ss += __shfl_xor(ss, off);
  double nrm = sqrt(ss); if (nrm < 1e-12) nrm = 1e-12;
  double sc = 45.254833995939045 / nrm;   // sqrt(2048)/||x||
  float* dst = xn + (size_t)row * DIM;
  for (int c = lane; c < DIM; c += 64) dst[c] = (float)((double)xr[c] * sc * (double)g[c]);
}

// --------------------------- bf16 MFMA NN GEMM with inline fp32->bf16 cast --
// C[M,N] = A[M,K] * B[K,N], both fp32 in memory, cast to bf16 in staging.
// 128x128 tile, BK=32, 4 waves (2x2 of 64x64). MFMA core identical to the
// round-1 gemm_nt that agreed with fp32 GEMM to 0.001.
__global__ __launch_bounds__(256) void gemm_nn_cast(
    const float* __restrict__ A, const float* __restrict__ B,
    float* __restrict__ C, int M, int N, int K) {
  __shared__ u16 As[128 * 40];   // [m][k]
  __shared__ u16 Bs[128 * 40];   // [n][k]
  int bm = blockIdx.x * 128;
  int bn = blockIdx.y * 128;
  int tid = threadIdx.x;
  int wid = tid >> 6, lane = tid & 63;
  int wr = wid >> 1, wc = wid & 1;
  int fr = lane & 15, fq = lane >> 4;

  // A staging: thread -> row ar (0..127), k-halves ak (0 or 16)
  int ar = tid >> 1;
  int ak = (tid & 1) * 16;
  // B staging: thread -> n (0..127), k = (tid>>7) + 2*it
  int bn_t = tid & 127;
  int bk_t = tid >> 7;

  f32x4 acc[4][4] = {};

  const u16* a_rd = As + (wr * 64 + fr) * 40 + fq * 8;
  const u16* b_rd = Bs + (wc * 64 + fr) * 40 + fq * 8;

  for (int k0 = 0; k0 < K; k0 += 32) {
    // prefetch globals to regs (fp32)
    const float4* ap = (const float4*)(A + (size_t)(bm + ar) * K + k0 + ak);
    float4 a0 = ap[0], a1 = ap[1], a2 = ap[2], a3 = ap[3];
    float breg[16];
    #pragma unroll
    for (int it = 0; it < 16; ++it)
      breg[it] = B[(size_t)(k0 + bk_t + it * 2) * N + bn + bn_t];

    __syncthreads();
    union { u16 h[16]; int4 q[2]; } cv;
    cv.h[0]=f2bf(a0.x); cv.h[1]=f2bf(a0.y); cv.h[2]=f2bf(a0.z); cv.h[3]=f2bf(a0.w);
    cv.h[4]=f2bf(a1.x); cv.h[5]=f2bf(a1.y); cv.h[6]=f2bf(a1.z); cv.h[7]=f2bf(a1.w);
    cv.h[8]=f2bf(a2.x); cv.h[9]=f2bf(a2.y); cv.h[10]=f2bf(a2.z); cv.h[11]=f2bf(a2.w);
    cv.h[12]=f2bf(a3.x); cv.h[13]=f2bf(a3.y); cv.h[14]=f2bf(a3.z); cv.h[15]=f2bf(a3.w);
    *(int4*)(As + ar * 40 + ak) = cv.q[0];
    *(int4*)(As + ar * 40 + ak + 8) = cv.q[1];
    #pragma unroll
    for (int it = 0; it < 16; ++it)
      Bs[bn_t * 40 + bk_t + it * 2] = f2bf(breg[it]);
    __syncthreads();

    bf16x8 af[4], bfr[4];
    #pragma unroll
    for (int m = 0; m < 4; ++m) af[m]  = *(const bf16x8*)(a_rd + m * 16 * 40);
    #pragma unroll
    for (int n = 0; n < 4; ++n) bfr[n] = *(const bf16x8*)(b_rd + n * 16 * 40);
    #pragma unroll
    for (int m = 0; m < 4; ++m)
      #pragma unroll
      for (int n = 0; n < 4; ++n)
        acc[m][n] = __builtin_amdgcn_mfma_f32_16x16x32_bf16(af[m], bfr[n], acc[m][n], 0, 0, 0);
  }
  #pragma unroll
  for (int m = 0; m < 4; ++m)
    #pragma unroll
    for (int n = 0; n < 4; ++n)
      #pragma unroll
      for (int r = 0; r < 4; ++r) {
        int row = bm + wr * 64 + m * 16 + fq * 4 + r;
        int col = bn + wc * 64 + n * 16 + fr;
        C[(size_t)row * N + col] = acc[m][n][r];
      }
}

// ---------------------------------- cached_kv: one thread per output element
// [VERIFIED round 4 — do not touch]
__global__ __launch_bounds__(256) void kvout_slow(
    const float* __restrict__ qkv, float* __restrict__ cached) {
  size_t gid = (size_t)blockIdx.x * 256 + threadIdx.x;  // 16,777,216
  int d = (int)(gid & 127);
  size_t r = gid >> 7;
  int n = (int)(r & 2047); r >>= 11;
  int h = (int)(r & 15);   r >>= 4;
  int b = (int)(r & 1);    r >>= 1;
  int kv = (int)r;         // 0=k, 1=v  (pre-RoPE)
  cached[gid] = qkv[(size_t)(b * SEQ + n) * NQKV + (size_t)(1 + kv) * DIM + h * DH + d];
}

// ------------------------------------------- RoPE in-place (fp64, per pair)
// [VERIFIED round 4 — do not touch]
__global__ __launch_bounds__(256) void rope_slow(float* __restrict__ qkv) {
  int gid = blockIdx.x * 256 + threadIdx.x;   // 8,388,608 pairs (q and k)
  int p = gid & 63;
  int n = (gid >> 6) & 2047;
  int h = (gid >> 17) & 15;
  int s = (gid >> 21) & 1;    // 0 = q, 1 = k
  int b = (gid >> 22) & 1;
  float* base = qkv + (size_t)(b * SEQ + n) * NQKV + s * DIM + h * DH + 2 * p;
  double inv = pow(10000.0, -(double)p / 64.0);  // 10000^(-2p/128)
  double ang = (double)n * inv;
  double cs = cos(ang), sn = sin(ang);
  double t0 = base[0], t1 = base[1];
  base[0] = (float)(t0 * cs - t1 * sn);
  base[1] = (float)(t1 * cs + t0 * sn);
}

// --------------------------------------------- fp32 VALU flash attention ----
// [byte-identical to round 2's attn_f32, which agreed with two other attns]
__global__ __launch_bounds__(64) void attn_f32(
    const float* __restrict__ qkv, float* __restrict__ ctx) {
  int row = blockIdx.x;            // ((b*16+h)*2048 + i)
  int i  = row & 2047;
  int bh = row >> 11;
  int b = bh >> 4, h = bh & 15;
  int lane = threadIdx.x;

  __shared__ float qs[128];
  __shared__ float ps[64];

  const float* Q  = qkv + (size_t)(b * SEQ + i) * NQKV + h * DH;
  const float* K0 = qkv + (size_t)(b * SEQ) * NQKV + DIM + h * DH;
  const float* V0 = K0 + DIM;

  qs[lane]      = Q[lane];
  qs[lane + 64] = Q[lane + 64];
  __syncthreads();

  float m = -3e38f, l = 0.f, o0 = 0.f, o1 = 0.f;
  const float scale = 0.08838834764831845f;

  for (int j0 = 0; j0 <= i; j0 += 64) {
    int jl = j0 + lane;
    float S = 0.f;
    const float4* Kr = (const float4*)(K0 + (size_t)jl * NQKV);
    #pragma unroll
    for (int c = 0; c < 32; ++c) {
      float4 k4 = Kr[c];
      S += qs[4*c] * k4.x + qs[4*c+1] * k4.y + qs[4*c+2] * k4.z + qs[4*c+3] * k4.w;
    }
    bool live = (jl <= i);
    S = live ? S * scale : -3e38f;

    float mx = S;
    #pragma unroll
    for (int off = 32; off >= 1; off >>= 1) mx = fmaxf(mx, __shfl_xor(mx, off));
    float mn = fmaxf(m, mx);
    float al = __expf(m - mn);
    m = mn;
    float p = live ? __expf(S - mn) : 0.f;
    float sum = p;
    #pragma unroll
    for (int off = 32; off >= 1; off >>= 1) sum += __shfl_xor(sum, off);
    l = l * al + sum;

    __syncthreads();
    ps[lane] = p;
    __syncthreads();

    o0 *= al; o1 *= al;
    int jmax = (i - j0 < 63) ? (i - j0) : 63;
    for (int jj = 0; jj <= jmax; ++jj) {
      float pj = ps[jj];
      const float* Vr = V0 + (size_t)(j0 + jj) * NQKV;
      o0 += pj * Vr[lane];
      o1 += pj * Vr[lane + 64];
    }
  }
  float* cr = ctx + (size_t)(b * SEQ + i) * DIM + h * DH;
  cr[lane]      = o0 / l;
  cr[lane + 64] = o1 / l;
}

// ----------------------------------------------------------------- launch ---
extern "C" void kernel_launch(void* const* d_in, const int* in_sizes, int n_in,
                              void* d_out, int out_size, void* d_ws, size_t ws_size,
                              hipStream_t stream) {
  // size-keyed input selection (sizes are pairwise distinct)
  const float *x = nullptr, *gamma = nullptr, *wq = nullptr, *wo = nullptr;
  for (int ii = 0; ii < n_in; ++ii) {
    switch (in_sizes[ii]) {
      case  8388608: x     = (const float*)d_in[ii]; break;
      case     2048: gamma = (const float*)d_in[ii]; break;
      case 12582912: wq    = (const float*)d_in[ii]; break;
      case  4194304: wo    = (const float*)d_in[ii]; break;
    }
  }
  if (!x || !gamma || !wq || !wo) {   // fallback: documented dict order
    x = (const float*)d_in[0]; gamma = (const float*)d_in[1];
    wq = (const float*)d_in[2]; wo = (const float*)d_in[3];
  }

  float* out    = (float*)d_out;           // (2,2048,2048)
  float* cached = out + 8388608;           // (2,2,16,2048,128)

  // ws: [0,33.55MB) xn (reused as ctx after QKV GEMM) ; [33.55,134.2MB) qkv
  // -- identical footprint to the passing round-4 layout.
  float* xn   = (float*)d_ws;
  float* ctx  = xn;
  float* qkvf = xn + (size_t)ROWS * DIM;

  rms_slow<<<ROWS, 64, 0, stream>>>(x, gamma, xn);
  gemm_nn_cast<<<dim3(ROWS / 128, NQKV / 128), 256, 0, stream>>>(xn, wq, qkvf, ROWS, NQKV, DIM);
  kvout_slow<<<65536, 256, 0, stream>>>(qkvf, cached);
  rope_slow<<<32768, 256, 0, stream>>>(qkvf);
  attn_f32<<<65536, 64, 0, stream>>>(qkvf, ctx);
  gemm_nn_cast<<<dim3(ROWS / 128, DIM / 128), 256, 0, stream>>>(ctx, wo, out, ROWS, DIM, DIM);
}

// Round 6
// 1268.606 us; speedup vs baseline: 10.2449x; 5.8962x over previous
//
#include <hip/hip_runtime.h>
#include <cstdint>
#include <cstddef>
#include <math.h>

#define SEQ   2048
#define DIM   2048
#define NQKV  6144
#define NH    16
#define DH    128
#define ROWS  4096   /* b*n */

typedef unsigned short u16;
typedef unsigned int u32;
typedef __attribute__((ext_vector_type(8))) short bf16x8;
typedef __attribute__((ext_vector_type(4))) float f32x4;

__device__ __forceinline__ u16 f2bf(float f) {
  union { float f; u32 u; } v;
  v.f = f;
  u32 r = v.u + 0x7FFFu + ((v.u >> 16) & 1u);
  return (u16)(r >> 16);
}

__device__ __forceinline__ bf16x8 ld_cast8(const float* p) {
  float4 f0 = *(const float4*)p;
  float4 f1 = *(const float4*)(p + 4);
  union { u16 h[8]; bf16x8 v; } cv;
  cv.h[0] = f2bf(f0.x); cv.h[1] = f2bf(f0.y); cv.h[2] = f2bf(f0.z); cv.h[3] = f2bf(f0.w);
  cv.h[4] = f2bf(f1.x); cv.h[5] = f2bf(f1.y); cv.h[6] = f2bf(f1.z); cv.h[7] = f2bf(f1.w);
  return cv.v;
}

// ------------------------------------------------ rmsnorm (fp64, 1 wave/row)
// [VERIFIED round 4 — do not touch]
__global__ __launch_bounds__(64) void rms_slow(
    const float* __restrict__ x, const float* __restrict__ g,
    float* __restrict__ xn) {
  int row = blockIdx.x, lane = threadIdx.x;
  const float* xr = x + (size_t)row * DIM;
  double ss = 0.0;
  for (int c = lane; c < DIM; c += 64) { double v = xr[c]; ss += v * v; }
  #pragma unroll
  for (int off = 32; off >= 1; off >>= 1) ss += __shfl_xor(ss, off);
  double nrm = sqrt(ss); if (nrm < 1e-12) nrm = 1e-12;
  double sc = 45.254833995939045 / nrm;   // sqrt(2048)/||x||
  float* dst = xn + (size_t)row * DIM;
  for (int c = lane; c < DIM; c += 64) dst[c] = (float)((double)xr[c] * sc * (double)g[c]);
}

// ------------------------- bf16 MFMA NN GEMM, A fp32-cast or native bf16 ----
// C[M,N] = A[M,K] * B[K,N]. B fp32 in memory, cast in staging.
// 128x128 tile, BK=32, 4 waves (2x2 of 64x64). MFMA core = round-1/5 verified.
template <typename AT>
__global__ __launch_bounds__(256) void gemm_nn(
    const AT* __restrict__ A, const float* __restrict__ B,
    float* __restrict__ C, int M, int N, int K) {
  __shared__ u16 As[128 * 40];   // [m][k]
  __shared__ u16 Bs[128 * 40];   // [n][k]
  int bm = blockIdx.x * 128;
  int bn = blockIdx.y * 128;
  int tid = threadIdx.x;
  int wid = tid >> 6, lane = tid & 63;
  int wr = wid >> 1, wc = wid & 1;
  int fr = lane & 15, fq = lane >> 4;

  int ar = tid >> 1;
  int ak = (tid & 1) * 16;
  int bn_t = tid & 127;
  int bk_t = tid >> 7;

  f32x4 acc[4][4] = {};

  const u16* a_rd = As + (wr * 64 + fr) * 40 + fq * 8;
  const u16* b_rd = Bs + (wc * 64 + fr) * 40 + fq * 8;

  for (int k0 = 0; k0 < K; k0 += 32) {
    int4 aq0, aq1;
    if constexpr (sizeof(AT) == 4) {
      const float4* ap = (const float4*)(A + (size_t)(bm + ar) * K + k0 + ak);
      float4 a0 = ap[0], a1 = ap[1], a2 = ap[2], a3 = ap[3];
      union { u16 h[16]; int4 q[2]; } cv;
      cv.h[0]=f2bf(a0.x); cv.h[1]=f2bf(a0.y); cv.h[2]=f2bf(a0.z); cv.h[3]=f2bf(a0.w);
      cv.h[4]=f2bf(a1.x); cv.h[5]=f2bf(a1.y); cv.h[6]=f2bf(a1.z); cv.h[7]=f2bf(a1.w);
      cv.h[8]=f2bf(a2.x); cv.h[9]=f2bf(a2.y); cv.h[10]=f2bf(a2.z); cv.h[11]=f2bf(a2.w);
      cv.h[12]=f2bf(a3.x); cv.h[13]=f2bf(a3.y); cv.h[14]=f2bf(a3.z); cv.h[15]=f2bf(a3.w);
      aq0 = cv.q[0]; aq1 = cv.q[1];
    } else {
      const int4* ap = (const int4*)(A + (size_t)(bm + ar) * K + k0 + ak);
      aq0 = ap[0]; aq1 = ap[1];
    }
    float breg[16];
    #pragma unroll
    for (int it = 0; it < 16; ++it)
      breg[it] = B[(size_t)(k0 + bk_t + it * 2) * N + bn + bn_t];

    __syncthreads();
    *(int4*)(As + ar * 40 + ak) = aq0;
    *(int4*)(As + ar * 40 + ak + 8) = aq1;
    #pragma unroll
    for (int it = 0; it < 16; ++it)
      Bs[bn_t * 40 + bk_t + it * 2] = f2bf(breg[it]);
    __syncthreads();

    bf16x8 af[4], bfr[4];
    #pragma unroll
    for (int m = 0; m < 4; ++m) af[m]  = *(const bf16x8*)(a_rd + m * 16 * 40);
    #pragma unroll
    for (int n = 0; n < 4; ++n) bfr[n] = *(const bf16x8*)(b_rd + n * 16 * 40);
    #pragma unroll
    for (int m = 0; m < 4; ++m)
      #pragma unroll
      for (int n = 0; n < 4; ++n)
        acc[m][n] = __builtin_amdgcn_mfma_f32_16x16x32_bf16(af[m], bfr[n], acc[m][n], 0, 0, 0);
  }
  #pragma unroll
  for (int m = 0; m < 4; ++m)
    #pragma unroll
    for (int n = 0; n < 4; ++n)
      #pragma unroll
      for (int r = 0; r < 4; ++r) {
        int row = bm + wr * 64 + m * 16 + fq * 4 + r;
        int col = bn + wc * 64 + n * 16 + fr;
        C[(size_t)row * N + col] = acc[m][n][r];
      }
}

// ---------------------------------- cached_kv: one thread per output element
// [VERIFIED round 4 — do not touch]
__global__ __launch_bounds__(256) void kvout_slow(
    const float* __restrict__ qkv, float* __restrict__ cached) {
  size_t gid = (size_t)blockIdx.x * 256 + threadIdx.x;  // 16,777,216
  int d = (int)(gid & 127);
  size_t r = gid >> 7;
  int n = (int)(r & 2047); r >>= 11;
  int h = (int)(r & 15);   r >>= 4;
  int b = (int)(r & 1);    r >>= 1;
  int kv = (int)r;         // 0=k, 1=v  (pre-RoPE)
  cached[gid] = qkv[(size_t)(b * SEQ + n) * NQKV + (size_t)(1 + kv) * DIM + h * DH + d];
}

// ------------------------------------------- RoPE in-place (fp64, per pair)
// [VERIFIED round 4 — do not touch]
__global__ __launch_bounds__(256) void rope_slow(float* __restrict__ qkv) {
  int gid = blockIdx.x * 256 + threadIdx.x;   // 8,388,608 pairs (q and k)
  int p = gid & 63;
  int n = (gid >> 6) & 2047;
  int h = (gid >> 17) & 15;
  int s = (gid >> 21) & 1;    // 0 = q, 1 = k
  int b = (gid >> 22) & 1;
  float* base = qkv + (size_t)(b * SEQ + n) * NQKV + s * DIM + h * DH + 2 * p;
  double inv = pow(10000.0, -(double)p / 64.0);  // 10000^(-2p/128)
  double ang = (double)n * inv;
  double cs = cos(ang), sn = sin(ang);
  double t0 = base[0], t1 = base[1];
  base[0] = (float)(t0 * cs - t1 * sn);
  base[1] = (float)(t1 * cs + t0 * sn);
}

// ------------------------- V transpose + cast -> vT[bh][d][n] (bf16) --------
__global__ void transpose_v_cast(const float* __restrict__ qkv,
                                 u16* __restrict__ vT) {
  int bh = blockIdx.z; int b = bh >> 4, h = bh & 15;
  int d0 = blockIdx.x * 32, n0 = blockIdx.y * 32;
  __shared__ float tile[32][33];
  int tx = threadIdx.x, ty = threadIdx.y;   // (32,8)
  const float* src = qkv + (size_t)(b * SEQ + n0) * NQKV + 2 * DIM + h * DH + d0;
  #pragma unroll
  for (int j = 0; j < 32; j += 8)
    tile[ty + j][tx] = src[(size_t)(ty + j) * NQKV + tx];
  __syncthreads();
  u16* dst = vT + ((size_t)bh * DH + d0) * SEQ + n0;
  #pragma unroll
  for (int j = 0; j < 32; j += 8)
    dst[(size_t)(ty + j) * SEQ + tx] = f2bf(tile[tx][ty + j]);
}

// ------------------------------- MFMA causal flash attention (round-0 port) -
// 4 waves/block, 16 q-rows/wave. Q,K fp32 -> in-register bf16 cast; V from
// bf16 vT. Softmax/P-LDS/PV structure identical to the round-0 kernel that
// agreed with the scalar implementations to 0.001.
__global__ __launch_bounds__(256) void attn_mfma(
    const float* __restrict__ qkv,  // roped q,k (fp32)
    const u16* __restrict__ vT,     // (32,128,2048) bf16
    u16* __restrict__ ctx) {        // (4096, 2048) bf16
  int qtile = blockIdx.x;           // 0..31
  int bh = blockIdx.y;              // 0..31
  int b = bh >> 4, h = bh & 15;
  int tid = threadIdx.x;
  int wid = tid >> 6, lane = tid & 63;
  int fr = lane & 15, fq = lane >> 4;
  int qr0 = qtile * 64 + wid * 16;

  __shared__ u16 P_lds[4][16 * 72];
  u16* Pw = &P_lds[wid][0];

  const float* Qb = qkv + (size_t)(b * SEQ) * NQKV + h * DH;
  const float* Kb = Qb + DIM;
  const u16* Vt = vT + (size_t)bh * DH * SEQ;

  bf16x8 qf[4];
  {
    const float* qrow = Qb + (size_t)(qr0 + fr) * NQKV + fq * 8;
    #pragma unroll
    for (int kk = 0; kk < 4; ++kk) qf[kk] = ld_cast8(qrow + kk * 32);
  }

  f32x4 acc[8] = {};
  float m_r[4], l_r[4];
  #pragma unroll
  for (int r = 0; r < 4; ++r) { m_r[r] = -3e38f; l_r[r] = 0.f; }

  const float scale = 0.08838834764831845f;
  int i0 = qr0 + fq * 4;

  for (int jt = 0; jt <= qtile; ++jt) {
    int j0 = jt * 64;
    f32x4 s[4];
    #pragma unroll
    for (int jf = 0; jf < 4; ++jf) {
      f32x4 sa = {0.f, 0.f, 0.f, 0.f};
      const float* krow = Kb + (size_t)(j0 + jf * 16 + fr) * NQKV + fq * 8;
      #pragma unroll
      for (int kk = 0; kk < 4; ++kk)
        sa = __builtin_amdgcn_mfma_f32_16x16x32_bf16(qf[kk], ld_cast8(krow + kk * 32), sa, 0, 0, 0);
      s[jf] = sa;
    }
    #pragma unroll
    for (int jf = 0; jf < 4; ++jf) {
      int j = j0 + jf * 16 + fr;
      #pragma unroll
      for (int r = 0; r < 4; ++r) {
        float v = s[jf][r] * scale;
        s[jf][r] = (j > i0 + r) ? -1e30f : v;
      }
    }
    float al[4], ls[4];
    #pragma unroll
    for (int r = 0; r < 4; ++r) {
      float mx = fmaxf(fmaxf(s[0][r], s[1][r]), fmaxf(s[2][r], s[3][r]));
      #pragma unroll
      for (int off = 8; off >= 1; off >>= 1) mx = fmaxf(mx, __shfl_xor(mx, off));
      float mn = fmaxf(m_r[r], mx);
      al[r] = __expf(m_r[r] - mn);
      m_r[r] = mn;
      float sum = 0.f;
      #pragma unroll
      for (int jf = 0; jf < 4; ++jf) {
        float p = __expf(s[jf][r] - mn);
        s[jf][r] = p;
        sum += p;
      }
      #pragma unroll
      for (int off = 8; off >= 1; off >>= 1) sum += __shfl_xor(sum, off);
      ls[r] = sum;
    }
    #pragma unroll
    for (int jf = 0; jf < 4; ++jf)
      #pragma unroll
      for (int r = 0; r < 4; ++r)
        Pw[(fq * 4 + r) * 72 + jf * 16 + fr] = f2bf(s[jf][r]);
    #pragma unroll
    for (int r = 0; r < 4; ++r) l_r[r] = l_r[r] * al[r] + ls[r];
    #pragma unroll
    for (int df = 0; df < 8; ++df)
      #pragma unroll
      for (int r = 0; r < 4; ++r) acc[df][r] *= al[r];

    bf16x8 pa0 = *(const bf16x8*)(Pw + fr * 72 + fq * 8);
    bf16x8 pa1 = *(const bf16x8*)(Pw + fr * 72 + 32 + fq * 8);
    #pragma unroll
    for (int df = 0; df < 8; ++df) {
      const u16* vrow = Vt + (size_t)(df * 16 + fr) * SEQ + j0 + fq * 8;
      bf16x8 v0 = *(const bf16x8*)(vrow);
      bf16x8 v1 = *(const bf16x8*)(vrow + 32);
      acc[df] = __builtin_amdgcn_mfma_f32_16x16x32_bf16(pa0, v0, acc[df], 0, 0, 0);
      acc[df] = __builtin_amdgcn_mfma_f32_16x16x32_bf16(pa1, v1, acc[df], 0, 0, 0);
    }
  }
  #pragma unroll
  for (int df = 0; df < 8; ++df)
    #pragma unroll
    for (int r = 0; r < 4; ++r) {
      int i = qr0 + fq * 4 + r;
      int d = df * 16 + fr;
      ctx[(size_t)(b * SEQ + i) * DIM + h * DH + d] = f2bf(acc[df][r] / l_r[r]);
    }
}

// ----------------------------------------------------------------- launch ---
extern "C" void kernel_launch(void* const* d_in, const int* in_sizes, int n_in,
                              void* d_out, int out_size, void* d_ws, size_t ws_size,
                              hipStream_t stream) {
  // size-keyed input selection (sizes are pairwise distinct)
  const float *x = nullptr, *gamma = nullptr, *wq = nullptr, *wo = nullptr;
  for (int ii = 0; ii < n_in; ++ii) {
    switch (in_sizes[ii]) {
      case  8388608: x     = (const float*)d_in[ii]; break;
      case     2048: gamma = (const float*)d_in[ii]; break;
      case 12582912: wq    = (const float*)d_in[ii]; break;
      case  4194304: wo    = (const float*)d_in[ii]; break;
    }
  }
  if (!x || !gamma || !wq || !wo) {   // fallback: documented dict order
    x = (const float*)d_in[0]; gamma = (const float*)d_in[1];
    wq = (const float*)d_in[2]; wo = (const float*)d_in[3];
  }

  float* out    = (float*)d_out;           // (2,2048,2048)
  float* cached = out + 8388608;           // (2,2,16,2048,128)

  // ws (134.2 MB, proven footprint):
  //   [0, 33.55MB)      xn (fp32) — dead after QKV GEMM; then reused as:
  //       [0, 16.78MB)      ctx (bf16)
  //       [16.78, 33.55MB)  vT  (bf16)
  //   [33.55, 134.2MB)  qkv (fp32)
  float* xn   = (float*)d_ws;
  u16*   ctx  = (u16*)d_ws;
  u16*   vT   = ctx + (size_t)ROWS * DIM;
  float* qkvf = (float*)((char*)d_ws + (size_t)ROWS * DIM * 4);

  rms_slow<<<ROWS, 64, 0, stream>>>(x, gamma, xn);
  gemm_nn<float><<<dim3(ROWS / 128, NQKV / 128), 256, 0, stream>>>(xn, wq, qkvf, ROWS, NQKV, DIM);
  kvout_slow<<<65536, 256, 0, stream>>>(qkvf, cached);
  rope_slow<<<32768, 256, 0, stream>>>(qkvf);
  transpose_v_cast<<<dim3(DH / 32, SEQ / 32, 32), dim3(32, 8), 0, stream>>>(qkvf, vT);
  attn_mfma<<<dim3(SEQ / 64, 32), 256, 0, stream>>>(qkvf, vT, ctx);
  gemm_nn<u16><<<dim3(ROWS / 128, DIM / 128), 256, 0, stream>>>(ctx, wo, out, ROWS, DIM, DIM);
}

// Round 7
// 854.377 us; speedup vs baseline: 15.2119x; 1.4848x over previous
//
#include <hip/hip_runtime.h>
#include <cstdint>
#include <cstddef>
#include <math.h>

#define SEQ   2048
#define DIM   2048
#define NQKV  6144
#define NH    16
#define DH    128
#define ROWS  4096   /* b*n */

typedef unsigned short u16;
typedef unsigned int u32;
typedef __attribute__((ext_vector_type(8))) short bf16x8;
typedef __attribute__((ext_vector_type(4))) float f32x4;

__device__ __forceinline__ u16 f2bf(float f) {
  union { float f; u32 u; } v;
  v.f = f;
  u32 r = v.u + 0x7FFFu + ((v.u >> 16) & 1u);
  return (u16)(r >> 16);
}

// ------------------------------------------------ rmsnorm (fp64, 1 wave/row)
// [VERIFIED round 4 — do not touch]
__global__ __launch_bounds__(64) void rms_slow(
    const float* __restrict__ x, const float* __restrict__ g,
    float* __restrict__ xn) {
  int row = blockIdx.x, lane = threadIdx.x;
  const float* xr = x + (size_t)row * DIM;
  double ss = 0.0;
  for (int c = lane; c < DIM; c += 64) { double v = xr[c]; ss += v * v; }
  #pragma unroll
  for (int off = 32; off >= 1; off >>= 1) ss += __shfl_xor(ss, off);
  double nrm = sqrt(ss); if (nrm < 1e-12) nrm = 1e-12;
  double sc = 45.254833995939045 / nrm;   // sqrt(2048)/||x||
  float* dst = xn + (size_t)row * DIM;
  for (int c = lane; c < DIM; c += 64) dst[c] = (float)((double)xr[c] * sc * (double)g[c]);
}

// ------------------------- bf16 MFMA NN GEMM, A fp32-cast or native bf16 ----
// [VERIFIED rounds 5/6 — unchanged]
template <typename AT>
__global__ __launch_bounds__(256) void gemm_nn(
    const AT* __restrict__ A, const float* __restrict__ B,
    float* __restrict__ C, int M, int N, int K) {
  __shared__ u16 As[128 * 40];   // [m][k]
  __shared__ u16 Bs[128 * 40];   // [n][k]
  int bm = blockIdx.x * 128;
  int bn = blockIdx.y * 128;
  int tid = threadIdx.x;
  int wid = tid >> 6, lane = tid & 63;
  int wr = wid >> 1, wc = wid & 1;
  int fr = lane & 15, fq = lane >> 4;

  int ar = tid >> 1;
  int ak = (tid & 1) * 16;
  int bn_t = tid & 127;
  int bk_t = tid >> 7;

  f32x4 acc[4][4] = {};

  const u16* a_rd = As + (wr * 64 + fr) * 40 + fq * 8;
  const u16* b_rd = Bs + (wc * 64 + fr) * 40 + fq * 8;

  for (int k0 = 0; k0 < K; k0 += 32) {
    int4 aq0, aq1;
    if constexpr (sizeof(AT) == 4) {
      const float4* ap = (const float4*)(A + (size_t)(bm + ar) * K + k0 + ak);
      float4 a0 = ap[0], a1 = ap[1], a2 = ap[2], a3 = ap[3];
      union { u16 h[16]; int4 q[2]; } cv;
      cv.h[0]=f2bf(a0.x); cv.h[1]=f2bf(a0.y); cv.h[2]=f2bf(a0.z); cv.h[3]=f2bf(a0.w);
      cv.h[4]=f2bf(a1.x); cv.h[5]=f2bf(a1.y); cv.h[6]=f2bf(a1.z); cv.h[7]=f2bf(a1.w);
      cv.h[8]=f2bf(a2.x); cv.h[9]=f2bf(a2.y); cv.h[10]=f2bf(a2.z); cv.h[11]=f2bf(a2.w);
      cv.h[12]=f2bf(a3.x); cv.h[13]=f2bf(a3.y); cv.h[14]=f2bf(a3.z); cv.h[15]=f2bf(a3.w);
      aq0 = cv.q[0]; aq1 = cv.q[1];
    } else {
      const int4* ap = (const int4*)(A + (size_t)(bm + ar) * K + k0 + ak);
      aq0 = ap[0]; aq1 = ap[1];
    }
    float breg[16];
    #pragma unroll
    for (int it = 0; it < 16; ++it)
      breg[it] = B[(size_t)(k0 + bk_t + it * 2) * N + bn + bn_t];

    __syncthreads();
    *(int4*)(As + ar * 40 + ak) = aq0;
    *(int4*)(As + ar * 40 + ak + 8) = aq1;
    #pragma unroll
    for (int it = 0; it < 16; ++it)
      Bs[bn_t * 40 + bk_t + it * 2] = f2bf(breg[it]);
    __syncthreads();

    bf16x8 af[4], bfr[4];
    #pragma unroll
    for (int m = 0; m < 4; ++m) af[m]  = *(const bf16x8*)(a_rd + m * 16 * 40);
    #pragma unroll
    for (int n = 0; n < 4; ++n) bfr[n] = *(const bf16x8*)(b_rd + n * 16 * 40);
    #pragma unroll
    for (int m = 0; m < 4; ++m)
      #pragma unroll
      for (int n = 0; n < 4; ++n)
        acc[m][n] = __builtin_amdgcn_mfma_f32_16x16x32_bf16(af[m], bfr[n], acc[m][n], 0, 0, 0);
  }
  #pragma unroll
  for (int m = 0; m < 4; ++m)
    #pragma unroll
    for (int n = 0; n < 4; ++n)
      #pragma unroll
      for (int r = 0; r < 4; ++r) {
        int row = bm + wr * 64 + m * 16 + fq * 4 + r;
        int col = bn + wc * 64 + n * 16 + fr;
        C[(size_t)row * N + col] = acc[m][n][r];
      }
}

// ---------------------------------- cached_kv: one thread per output element
// [VERIFIED round 4 — do not touch]
__global__ __launch_bounds__(256) void kvout_slow(
    const float* __restrict__ qkv, float* __restrict__ cached) {
  size_t gid = (size_t)blockIdx.x * 256 + threadIdx.x;  // 16,777,216
  int d = (int)(gid & 127);
  size_t r = gid >> 7;
  int n = (int)(r & 2047); r >>= 11;
  int h = (int)(r & 15);   r >>= 4;
  int b = (int)(r & 1);    r >>= 1;
  int kv = (int)r;         // 0=k, 1=v  (pre-RoPE)
  cached[gid] = qkv[(size_t)(b * SEQ + n) * NQKV + (size_t)(1 + kv) * DIM + h * DH + d];
}

// ------------------------------------------- RoPE in-place (fp64, per pair)
// [VERIFIED round 4 — do not touch]
__global__ __launch_bounds__(256) void rope_slow(float* __restrict__ qkv) {
  int gid = blockIdx.x * 256 + threadIdx.x;   // 8,388,608 pairs (q and k)
  int p = gid & 63;
  int n = (gid >> 6) & 2047;
  int h = (gid >> 17) & 15;
  int s = (gid >> 21) & 1;    // 0 = q, 1 = k
  int b = (gid >> 22) & 1;
  float* base = qkv + (size_t)(b * SEQ + n) * NQKV + s * DIM + h * DH + 2 * p;
  double inv = pow(10000.0, -(double)p / 64.0);  // 10000^(-2p/128)
  double ang = (double)n * inv;
  double cs = cos(ang), sn = sin(ang);
  double t0 = base[0], t1 = base[1];
  base[0] = (float)(t0 * cs - t1 * sn);
  base[1] = (float)(t1 * cs + t0 * sn);
}

// ------------------------- V transpose + cast -> vT[bh][d][n] (bf16) --------
// [VERIFIED round 6 — unchanged]
__global__ void transpose_v_cast(const float* __restrict__ qkv,
                                 u16* __restrict__ vT) {
  int bh = blockIdx.z; int b = bh >> 4, h = bh & 15;
  int d0 = blockIdx.x * 32, n0 = blockIdx.y * 32;
  __shared__ float tile[32][33];
  int tx = threadIdx.x, ty = threadIdx.y;   // (32,8)
  const float* src = qkv + (size_t)(b * SEQ + n0) * NQKV + 2 * DIM + h * DH + d0;
  #pragma unroll
  for (int j = 0; j < 32; j += 8)
    tile[ty + j][tx] = src[(size_t)(ty + j) * NQKV + tx];
  __syncthreads();
  u16* dst = vT + ((size_t)bh * DH + d0) * SEQ + n0;
  #pragma unroll
  for (int j = 0; j < 32; j += 8)
    dst[(size_t)(ty + j) * SEQ + tx] = f2bf(tile[tx][ty + j]);
}

// ----------------- pack post-RoPE q,k as bf16 into the dead fp32-V region ---
// Row layout (fp32): [q 2048][k 2048][v 2048]. V is dead after
// transpose_v_cast, so its 8 KB hold q(2048 u16) + k(2048 u16) packed.
// u16 slot within row: q -> 8192 + h*128 + d ; k -> 10240 + h*128 + d.
__global__ __launch_bounds__(256) void pack_qk(float* __restrict__ qkv) {
  int row = blockIdx.x;           // 0..4095
  int t = threadIdx.x;            // 16 elems each over q+k (4096 elems)
  const float* src = qkv + (size_t)row * NQKV + t * 16;
  float4 f0 = ((const float4*)src)[0];
  float4 f1 = ((const float4*)src)[1];
  float4 f2 = ((const float4*)src)[2];
  float4 f3 = ((const float4*)src)[3];
  union { u16 h[16]; int4 q[2]; } cv;
  cv.h[0]=f2bf(f0.x);  cv.h[1]=f2bf(f0.y);  cv.h[2]=f2bf(f0.z);  cv.h[3]=f2bf(f0.w);
  cv.h[4]=f2bf(f1.x);  cv.h[5]=f2bf(f1.y);  cv.h[6]=f2bf(f1.z);  cv.h[7]=f2bf(f1.w);
  cv.h[8]=f2bf(f2.x);  cv.h[9]=f2bf(f2.y);  cv.h[10]=f2bf(f2.z); cv.h[11]=f2bf(f2.w);
  cv.h[12]=f2bf(f3.x); cv.h[13]=f2bf(f3.y); cv.h[14]=f2bf(f3.z); cv.h[15]=f2bf(f3.w);
  u16* dst = (u16*)(qkv + (size_t)row * NQKV) + 8192 + t * 16;
  ((int4*)dst)[0] = cv.q[0];
  ((int4*)dst)[1] = cv.q[1];
}

// --------------------- MFMA causal flash attention, 1 wave / 16 q-rows ------
// Tile math byte-identical to the round-6-verified kernel; only the grid
// decomposition (1 wave per block) and Q/K source (packed bf16) changed.
__global__ __launch_bounds__(64) void attn_mfma16(
    const u16* __restrict__ qkp,   // u16 view of qkvf (packed q,k in V region)
    const u16* __restrict__ vT,    // (32,128,2048) bf16
    u16* __restrict__ ctx) {       // (4096, 2048) bf16
  int qt = 127 - blockIdx.x;       // longest blocks first
  int bh = blockIdx.y;             // 0..31
  int b = bh >> 4, h = bh & 15;
  int lane = threadIdx.x;
  int fr = lane & 15, fq = lane >> 4;
  int qr0 = qt * 16;

  __shared__ u16 Pw[16 * 72];

  const size_t rstr = 2 * NQKV;    // u16 per row
  const u16* Qb = qkp + (size_t)(b * SEQ) * rstr + 8192 + h * 128;
  const u16* Kb = qkp + (size_t)(b * SEQ) * rstr + 10240 + h * 128;
  const u16* Vt = vT + (size_t)bh * DH * SEQ;

  bf16x8 qf[4];
  {
    const u16* qrow = Qb + (size_t)(qr0 + fr) * rstr + fq * 8;
    #pragma unroll
    for (int kk = 0; kk < 4; ++kk) qf[kk] = *(const bf16x8*)(qrow + kk * 32);
  }

  f32x4 acc[8] = {};
  float m_r[4], l_r[4];
  #pragma unroll
  for (int r = 0; r < 4; ++r) { m_r[r] = -3e38f; l_r[r] = 0.f; }

  const float scale = 0.08838834764831845f;
  int i0 = qr0 + fq * 4;
  int jt_end = qt >> 2;

  for (int jt = 0; jt <= jt_end; ++jt) {
    int j0 = jt * 64;
    f32x4 s[4];
    #pragma unroll
    for (int jf = 0; jf < 4; ++jf) {
      f32x4 sa = {0.f, 0.f, 0.f, 0.f};
      const u16* krow = Kb + (size_t)(j0 + jf * 16 + fr) * rstr + fq * 8;
      #pragma unroll
      for (int kk = 0; kk < 4; ++kk) {
        bf16x8 kf = *(const bf16x8*)(krow + kk * 32);
        sa = __builtin_amdgcn_mfma_f32_16x16x32_bf16(qf[kk], kf, sa, 0, 0, 0);
      }
      s[jf] = sa;
    }
    #pragma unroll
    for (int jf = 0; jf < 4; ++jf) {
      int j = j0 + jf * 16 + fr;
      #pragma unroll
      for (int r = 0; r < 4; ++r) {
        float v = s[jf][r] * scale;
        s[jf][r] = (j > i0 + r) ? -1e30f : v;
      }
    }
    float al[4], ls[4];
    #pragma unroll
    for (int r = 0; r < 4; ++r) {
      float mx = fmaxf(fmaxf(s[0][r], s[1][r]), fmaxf(s[2][r], s[3][r]));
      #pragma unroll
      for (int off = 8; off >= 1; off >>= 1) mx = fmaxf(mx, __shfl_xor(mx, off));
      float mn = fmaxf(m_r[r], mx);
      al[r] = __expf(m_r[r] - mn);
      m_r[r] = mn;
      float sum = 0.f;
      #pragma unroll
      for (int jf = 0; jf < 4; ++jf) {
        float p = __expf(s[jf][r] - mn);
        s[jf][r] = p;
        sum += p;
      }
      #pragma unroll
      for (int off = 8; off >= 1; off >>= 1) sum += __shfl_xor(sum, off);
      ls[r] = sum;
    }
    #pragma unroll
    for (int jf = 0; jf < 4; ++jf)
      #pragma unroll
      for (int r = 0; r < 4; ++r)
        Pw[(fq * 4 + r) * 72 + jf * 16 + fr] = f2bf(s[jf][r]);
    #pragma unroll
    for (int r = 0; r < 4; ++r) l_r[r] = l_r[r] * al[r] + ls[r];
    #pragma unroll
    for (int df = 0; df < 8; ++df)
      #pragma unroll
      for (int r = 0; r < 4; ++r) acc[df][r] *= al[r];

    bf16x8 pa0 = *(const bf16x8*)(Pw + fr * 72 + fq * 8);
    bf16x8 pa1 = *(const bf16x8*)(Pw + fr * 72 + 32 + fq * 8);
    #pragma unroll
    for (int df = 0; df < 8; ++df) {
      const u16* vrow = Vt + (size_t)(df * 16 + fr) * SEQ + j0 + fq * 8;
      bf16x8 v0 = *(const bf16x8*)(vrow);
      bf16x8 v1 = *(const bf16x8*)(vrow + 32);
      acc[df] = __builtin_amdgcn_mfma_f32_16x16x32_bf16(pa0, v0, acc[df], 0, 0, 0);
      acc[df] = __builtin_amdgcn_mfma_f32_16x16x32_bf16(pa1, v1, acc[df], 0, 0, 0);
    }
  }
  #pragma unroll
  for (int df = 0; df < 8; ++df)
    #pragma unroll
    for (int r = 0; r < 4; ++r) {
      int i = qr0 + fq * 4 + r;
      int d = df * 16 + fr;
      ctx[(size_t)(b * SEQ + i) * DIM + h * DH + d] = f2bf(acc[df][r] / l_r[r]);
    }
}

// ----------------------------------------------------------------- launch ---
extern "C" void kernel_launch(void* const* d_in, const int* in_sizes, int n_in,
                              void* d_out, int out_size, void* d_ws, size_t ws_size,
                              hipStream_t stream) {
  // size-keyed input selection (sizes are pairwise distinct)
  const float *x = nullptr, *gamma = nullptr, *wq = nullptr, *wo = nullptr;
  for (int ii = 0; ii < n_in; ++ii) {
    switch (in_sizes[ii]) {
      case  8388608: x     = (const float*)d_in[ii]; break;
      case     2048: gamma = (const float*)d_in[ii]; break;
      case 12582912: wq    = (const float*)d_in[ii]; break;
      case  4194304: wo    = (const float*)d_in[ii]; break;
    }
  }
  if (!x || !gamma || !wq || !wo) {   // fallback: documented dict order
    x = (const float*)d_in[0]; gamma = (const float*)d_in[1];
    wq = (const float*)d_in[2]; wo = (const float*)d_in[3];
  }

  float* out    = (float*)d_out;           // (2,2048,2048)
  float* cached = out + 8388608;           // (2,2,16,2048,128)

  // ws (134.2 MB, proven footprint):
  //   [0, 33.55MB)      xn (fp32) — dead after QKV GEMM; then reused as:
  //       [0, 16.78MB)      ctx (bf16)
  //       [16.78, 33.55MB)  vT  (bf16)
  //   [33.55, 134.2MB)  qkv (fp32; V third repurposed for packed bf16 q,k)
  float* xn   = (float*)d_ws;
  u16*   ctx  = (u16*)d_ws;
  u16*   vT   = ctx + (size_t)ROWS * DIM;
  float* qkvf = (float*)((char*)d_ws + (size_t)ROWS * DIM * 4);

  rms_slow<<<ROWS, 64, 0, stream>>>(x, gamma, xn);
  gemm_nn<float><<<dim3(ROWS / 128, NQKV / 128), 256, 0, stream>>>(xn, wq, qkvf, ROWS, NQKV, DIM);
  kvout_slow<<<65536, 256, 0, stream>>>(qkvf, cached);
  rope_slow<<<32768, 256, 0, stream>>>(qkvf);
  transpose_v_cast<<<dim3(DH / 32, SEQ / 32, 32), dim3(32, 8), 0, stream>>>(qkvf, vT);
  pack_qk<<<ROWS, 256, 0, stream>>>(qkvf);
  attn_mfma16<<<dim3(128, 32), 64, 0, stream>>>((const u16*)qkvf, vT, ctx);
  gemm_nn<u16><<<dim3(ROWS / 128, DIM / 128), 256, 0, stream>>>(ctx, wo, out, ROWS, DIM, DIM);
}

// Round 8
// 799.761 us; speedup vs baseline: 16.2508x; 1.0683x over previous
//
#include <hip/hip_runtime.h>
#include <cstdint>
#include <cstddef>
#include <math.h>

#define SEQ   2048
#define DIM   2048
#define NQKV  6144
#define NH    16
#define DH    128
#define ROWS  4096   /* b*n */

typedef unsigned short u16;
typedef unsigned int u32;
typedef __attribute__((ext_vector_type(8))) short bf16x8;
typedef __attribute__((ext_vector_type(4))) float f32x4;

__device__ __forceinline__ u16 f2bf(float f) {
  union { float f; u32 u; } v;
  v.f = f;
  u32 r = v.u + 0x7FFFu + ((v.u >> 16) & 1u);
  return (u16)(r >> 16);
}

// ------------------------------------------------ rmsnorm (fp64, 1 wave/row)
// [VERIFIED round 4 — do not touch]
__global__ __launch_bounds__(64) void rms_slow(
    const float* __restrict__ x, const float* __restrict__ g,
    float* __restrict__ xn) {
  int row = blockIdx.x, lane = threadIdx.x;
  const float* xr = x + (size_t)row * DIM;
  double ss = 0.0;
  for (int c = lane; c < DIM; c += 64) { double v = xr[c]; ss += v * v; }
  #pragma unroll
  for (int off = 32; off >= 1; off >>= 1) ss += __shfl_xor(ss, off);
  double nrm = sqrt(ss); if (nrm < 1e-12) nrm = 1e-12;
  double sc = 45.254833995939045 / nrm;   // sqrt(2048)/||x||
  float* dst = xn + (size_t)row * DIM;
  for (int c = lane; c < DIM; c += 64) dst[c] = (float)((double)xr[c] * sc * (double)g[c]);
}

// ------------------------- bf16 MFMA NN GEMM, A fp32-cast or native bf16 ----
// [VERIFIED rounds 5/6 — unchanged]
template <typename AT>
__global__ __launch_bounds__(256) void gemm_nn(
    const AT* __restrict__ A, const float* __restrict__ B,
    float* __restrict__ C, int M, int N, int K) {
  __shared__ u16 As[128 * 40];   // [m][k]
  __shared__ u16 Bs[128 * 40];   // [n][k]
  int bm = blockIdx.x * 128;
  int bn = blockIdx.y * 128;
  int tid = threadIdx.x;
  int wid = tid >> 6, lane = tid & 63;
  int wr = wid >> 1, wc = wid & 1;
  int fr = lane & 15, fq = lane >> 4;

  int ar = tid >> 1;
  int ak = (tid & 1) * 16;
  int bn_t = tid & 127;
  int bk_t = tid >> 7;

  f32x4 acc[4][4] = {};

  const u16* a_rd = As + (wr * 64 + fr) * 40 + fq * 8;
  const u16* b_rd = Bs + (wc * 64 + fr) * 40 + fq * 8;

  for (int k0 = 0; k0 < K; k0 += 32) {
    int4 aq0, aq1;
    if constexpr (sizeof(AT) == 4) {
      const float4* ap = (const float4*)(A + (size_t)(bm + ar) * K + k0 + ak);
      float4 a0 = ap[0], a1 = ap[1], a2 = ap[2], a3 = ap[3];
      union { u16 h[16]; int4 q[2]; } cv;
      cv.h[0]=f2bf(a0.x); cv.h[1]=f2bf(a0.y); cv.h[2]=f2bf(a0.z); cv.h[3]=f2bf(a0.w);
      cv.h[4]=f2bf(a1.x); cv.h[5]=f2bf(a1.y); cv.h[6]=f2bf(a1.z); cv.h[7]=f2bf(a1.w);
      cv.h[8]=f2bf(a2.x); cv.h[9]=f2bf(a2.y); cv.h[10]=f2bf(a2.z); cv.h[11]=f2bf(a2.w);
      cv.h[12]=f2bf(a3.x); cv.h[13]=f2bf(a3.y); cv.h[14]=f2bf(a3.z); cv.h[15]=f2bf(a3.w);
      aq0 = cv.q[0]; aq1 = cv.q[1];
    } else {
      const int4* ap = (const int4*)(A + (size_t)(bm + ar) * K + k0 + ak);
      aq0 = ap[0]; aq1 = ap[1];
    }
    float breg[16];
    #pragma unroll
    for (int it = 0; it < 16; ++it)
      breg[it] = B[(size_t)(k0 + bk_t + it * 2) * N + bn + bn_t];

    __syncthreads();
    *(int4*)(As + ar * 40 + ak) = aq0;
    *(int4*)(As + ar * 40 + ak + 8) = aq1;
    #pragma unroll
    for (int it = 0; it < 16; ++it)
      Bs[bn_t * 40 + bk_t + it * 2] = f2bf(breg[it]);
    __syncthreads();

    bf16x8 af[4], bfr[4];
    #pragma unroll
    for (int m = 0; m < 4; ++m) af[m]  = *(const bf16x8*)(a_rd + m * 16 * 40);
    #pragma unroll
    for (int n = 0; n < 4; ++n) bfr[n] = *(const bf16x8*)(b_rd + n * 16 * 40);
    #pragma unroll
    for (int m = 0; m < 4; ++m)
      #pragma unroll
      for (int n = 0; n < 4; ++n)
        acc[m][n] = __builtin_amdgcn_mfma_f32_16x16x32_bf16(af[m], bfr[n], acc[m][n], 0, 0, 0);
  }
  #pragma unroll
  for (int m = 0; m < 4; ++m)
    #pragma unroll
    for (int n = 0; n < 4; ++n)
      #pragma unroll
      for (int r = 0; r < 4; ++r) {
        int row = bm + wr * 64 + m * 16 + fq * 4 + r;
        int col = bn + wc * 64 + n * 16 + fr;
        C[(size_t)row * N + col] = acc[m][n][r];
      }
}

// ---------------------------------- cached_kv: one thread per output element
// [VERIFIED round 4 — do not touch]
__global__ __launch_bounds__(256) void kvout_slow(
    const float* __restrict__ qkv, float* __restrict__ cached) {
  size_t gid = (size_t)blockIdx.x * 256 + threadIdx.x;  // 16,777,216
  int d = (int)(gid & 127);
  size_t r = gid >> 7;
  int n = (int)(r & 2047); r >>= 11;
  int h = (int)(r & 15);   r >>= 4;
  int b = (int)(r & 1);    r >>= 1;
  int kv = (int)r;         // 0=k, 1=v  (pre-RoPE)
  cached[gid] = qkv[(size_t)(b * SEQ + n) * NQKV + (size_t)(1 + kv) * DIM + h * DH + d];
}

// ------------------------------------------- RoPE in-place (fp64, per pair)
// [VERIFIED round 4 — do not touch]
__global__ __launch_bounds__(256) void rope_slow(float* __restrict__ qkv) {
  int gid = blockIdx.x * 256 + threadIdx.x;   // 8,388,608 pairs (q and k)
  int p = gid & 63;
  int n = (gid >> 6) & 2047;
  int h = (gid >> 17) & 15;
  int s = (gid >> 21) & 1;    // 0 = q, 1 = k
  int b = (gid >> 22) & 1;
  float* base = qkv + (size_t)(b * SEQ + n) * NQKV + s * DIM + h * DH + 2 * p;
  double inv = pow(10000.0, -(double)p / 64.0);  // 10000^(-2p/128)
  double ang = (double)n * inv;
  double cs = cos(ang), sn = sin(ang);
  double t0 = base[0], t1 = base[1];
  base[0] = (float)(t0 * cs - t1 * sn);
  base[1] = (float)(t1 * cs + t0 * sn);
}

// ------------------------- V transpose + cast -> vT[bh][d][n] (bf16) --------
// [VERIFIED round 6 — unchanged]
__global__ void transpose_v_cast(const float* __restrict__ qkv,
                                 u16* __restrict__ vT) {
  int bh = blockIdx.z; int b = bh >> 4, h = bh & 15;
  int d0 = blockIdx.x * 32, n0 = blockIdx.y * 32;
  __shared__ float tile[32][33];
  int tx = threadIdx.x, ty = threadIdx.y;   // (32,8)
  const float* src = qkv + (size_t)(b * SEQ + n0) * NQKV + 2 * DIM + h * DH + d0;
  #pragma unroll
  for (int j = 0; j < 32; j += 8)
    tile[ty + j][tx] = src[(size_t)(ty + j) * NQKV + tx];
  __syncthreads();
  u16* dst = vT + ((size_t)bh * DH + d0) * SEQ + n0;
  #pragma unroll
  for (int j = 0; j < 32; j += 8)
    dst[(size_t)(ty + j) * SEQ + tx] = f2bf(tile[tx][ty + j]);
}

// ----------------- pack post-RoPE q,k as bf16 into the dead fp32-V region ---
// [VERIFIED round 7 — unchanged]
__global__ __launch_bounds__(256) void pack_qk(float* __restrict__ qkv) {
  int row = blockIdx.x;           // 0..4095
  int t = threadIdx.x;            // 16 elems each over q+k (4096 elems)
  const float* src = qkv + (size_t)row * NQKV + t * 16;
  float4 f0 = ((const float4*)src)[0];
  float4 f1 = ((const float4*)src)[1];
  float4 f2 = ((const float4*)src)[2];
  float4 f3 = ((const float4*)src)[3];
  union { u16 h[16]; int4 q[2]; } cv;
  cv.h[0]=f2bf(f0.x);  cv.h[1]=f2bf(f0.y);  cv.h[2]=f2bf(f0.z);  cv.h[3]=f2bf(f0.w);
  cv.h[4]=f2bf(f1.x);  cv.h[5]=f2bf(f1.y);  cv.h[6]=f2bf(f1.z);  cv.h[7]=f2bf(f1.w);
  cv.h[8]=f2bf(f2.x);  cv.h[9]=f2bf(f2.y);  cv.h[10]=f2bf(f2.z); cv.h[11]=f2bf(f2.w);
  cv.h[12]=f2bf(f3.x); cv.h[13]=f2bf(f3.y); cv.h[14]=f2bf(f3.z); cv.h[15]=f2bf(f3.w);
  u16* dst = (u16*)(qkv + (size_t)row * NQKV) + 8192 + t * 16;
  ((int4*)dst)[0] = cv.q[0];
  ((int4*)dst)[1] = cv.q[1];
}

// --------------------- MFMA causal flash attention, 1 wave / 16 q-rows ------
// Round-7 kernel + in-register pipelining: K tile prefetched one tile ahead
// into the same registers (dead after QK), V loads hoisted above softmax.
// Tile math (QK/mask/softmax/P-LDS/PV/epilogue) byte-identical to round 7.
__global__ __launch_bounds__(64) void attn_mfma16(
    const u16* __restrict__ qkp,   // u16 view of qkvf (packed q,k in V region)
    const u16* __restrict__ vT,    // (32,128,2048) bf16
    u16* __restrict__ ctx) {       // (4096, 2048) bf16
  int qt = 127 - blockIdx.x;       // longest blocks first
  int bh = blockIdx.y;             // 0..31
  int b = bh >> 4, h = bh & 15;
  int lane = threadIdx.x;
  int fr = lane & 15, fq = lane >> 4;
  int qr0 = qt * 16;

  __shared__ u16 Pw[16 * 72];

  const size_t rstr = 2 * NQKV;    // u16 per row
  const u16* Qb = qkp + (size_t)(b * SEQ) * rstr + 8192 + h * 128;
  const u16* Kb = qkp + (size_t)(b * SEQ) * rstr + 10240 + h * 128;
  const u16* Vt = vT + (size_t)bh * DH * SEQ;

  bf16x8 qf[4];
  {
    const u16* qrow = Qb + (size_t)(qr0 + fr) * rstr + fq * 8;
    #pragma unroll
    for (int kk = 0; kk < 4; ++kk) qf[kk] = *(const bf16x8*)(qrow + kk * 32);
  }

  f32x4 acc[8] = {};
  float m_r[4], l_r[4];
  #pragma unroll
  for (int r = 0; r < 4; ++r) { m_r[r] = -3e38f; l_r[r] = 0.f; }

  const float scale = 0.08838834764831845f;
  int i0 = qr0 + fq * 4;
  int jt_end = qt >> 2;

  // register-resident K and V tiles
  bf16x8 kreg[16];   // [jf][kk]
  bf16x8 vreg[16];   // [df][half]

  // preload K tile 0
  #pragma unroll
  for (int jf = 0; jf < 4; ++jf) {
    const u16* krow = Kb + (size_t)(jf * 16 + fr) * rstr + fq * 8;
    #pragma unroll
    for (int kk = 0; kk < 4; ++kk) kreg[jf * 4 + kk] = *(const bf16x8*)(krow + kk * 32);
  }

  for (int jt = 0; jt <= jt_end; ++jt) {
    int j0 = jt * 64;

    // issue V loads for THIS tile now — consumed after softmax (~1k cy later)
    #pragma unroll
    for (int df = 0; df < 8; ++df) {
      const u16* vrow = Vt + (size_t)(df * 16 + fr) * SEQ + j0 + fq * 8;
      vreg[df * 2]     = *(const bf16x8*)(vrow);
      vreg[df * 2 + 1] = *(const bf16x8*)(vrow + 32);
    }

    // QK^T from register-resident K
    f32x4 s[4];
    #pragma unroll
    for (int jf = 0; jf < 4; ++jf) {
      f32x4 sa = {0.f, 0.f, 0.f, 0.f};
      #pragma unroll
      for (int kk = 0; kk < 4; ++kk)
        sa = __builtin_amdgcn_mfma_f32_16x16x32_bf16(qf[kk], kreg[jf * 4 + kk], sa, 0, 0, 0);
      s[jf] = sa;
    }

    // prefetch NEXT K tile into the same (now dead) registers;
    // refill latency hides under mask+softmax+P below.
    if (jt < jt_end) {
      int jn0 = j0 + 64;
      #pragma unroll
      for (int jf = 0; jf < 4; ++jf) {
        const u16* krow = Kb + (size_t)(jn0 + jf * 16 + fr) * rstr + fq * 8;
        #pragma unroll
        for (int kk = 0; kk < 4; ++kk) kreg[jf * 4 + kk] = *(const bf16x8*)(krow + kk * 32);
      }
    }

    #pragma unroll
    for (int jf = 0; jf < 4; ++jf) {
      int j = j0 + jf * 16 + fr;
      #pragma unroll
      for (int r = 0; r < 4; ++r) {
        float v = s[jf][r] * scale;
        s[jf][r] = (j > i0 + r) ? -1e30f : v;
      }
    }
    float al[4], ls[4];
    #pragma unroll
    for (int r = 0; r < 4; ++r) {
      float mx = fmaxf(fmaxf(s[0][r], s[1][r]), fmaxf(s[2][r], s[3][r]));
      #pragma unroll
      for (int off = 8; off >= 1; off >>= 1) mx = fmaxf(mx, __shfl_xor(mx, off));
      float mn = fmaxf(m_r[r], mx);
      al[r] = __expf(m_r[r] - mn);
      m_r[r] = mn;
      float sum = 0.f;
      #pragma unroll
      for (int jf = 0; jf < 4; ++jf) {
        float p = __expf(s[jf][r] - mn);
        s[jf][r] = p;
        sum += p;
      }
      #pragma unroll
      for (int off = 8; off >= 1; off >>= 1) sum += __shfl_xor(sum, off);
      ls[r] = sum;
    }
    #pragma unroll
    for (int jf = 0; jf < 4; ++jf)
      #pragma unroll
      for (int r = 0; r < 4; ++r)
        Pw[(fq * 4 + r) * 72 + jf * 16 + fr] = f2bf(s[jf][r]);
    #pragma unroll
    for (int r = 0; r < 4; ++r) l_r[r] = l_r[r] * al[r] + ls[r];
    #pragma unroll
    for (int df = 0; df < 8; ++df)
      #pragma unroll
      for (int r = 0; r < 4; ++r) acc[df][r] *= al[r];

    bf16x8 pa0 = *(const bf16x8*)(Pw + fr * 72 + fq * 8);
    bf16x8 pa1 = *(const bf16x8*)(Pw + fr * 72 + 32 + fq * 8);
    #pragma unroll
    for (int df = 0; df < 8; ++df) {
      acc[df] = __builtin_amdgcn_mfma_f32_16x16x32_bf16(pa0, vreg[df * 2],     acc[df], 0, 0, 0);
      acc[df] = __builtin_amdgcn_mfma_f32_16x16x32_bf16(pa1, vreg[df * 2 + 1], acc[df], 0, 0, 0);
    }
  }
  #pragma unroll
  for (int df = 0; df < 8; ++df)
    #pragma unroll
    for (int r = 0; r < 4; ++r) {
      int i = qr0 + fq * 4 + r;
      int d = df * 16 + fr;
      ctx[(size_t)(b * SEQ + i) * DIM + h * DH + d] = f2bf(acc[df][r] / l_r[r]);
    }
}

// ----------------------------------------------------------------- launch ---
extern "C" void kernel_launch(void* const* d_in, const int* in_sizes, int n_in,
                              void* d_out, int out_size, void* d_ws, size_t ws_size,
                              hipStream_t stream) {
  // size-keyed input selection (sizes are pairwise distinct)
  const float *x = nullptr, *gamma = nullptr, *wq = nullptr, *wo = nullptr;
  for (int ii = 0; ii < n_in; ++ii) {
    switch (in_sizes[ii]) {
      case  8388608: x     = (const float*)d_in[ii]; break;
      case     2048: gamma = (const float*)d_in[ii]; break;
      case 12582912: wq    = (const float*)d_in[ii]; break;
      case  4194304: wo    = (const float*)d_in[ii]; break;
    }
  }
  if (!x || !gamma || !wq || !wo) {   // fallback: documented dict order
    x = (const float*)d_in[0]; gamma = (const float*)d_in[1];
    wq = (const float*)d_in[2]; wo = (const float*)d_in[3];
  }

  float* out    = (float*)d_out;           // (2,2048,2048)
  float* cached = out + 8388608;           // (2,2,16,2048,128)

  // ws (134.2 MB, proven footprint):
  //   [0, 33.55MB)      xn (fp32) — dead after QKV GEMM; then reused as:
  //       [0, 16.78MB)      ctx (bf16)
  //       [16.78, 33.55MB)  vT  (bf16)
  //   [33.55, 134.2MB)  qkv (fp32; V third repurposed for packed bf16 q,k)
  float* xn   = (float*)d_ws;
  u16*   ctx  = (u16*)d_ws;
  u16*   vT   = ctx + (size_t)ROWS * DIM;
  float* qkvf = (float*)((char*)d_ws + (size_t)ROWS * DIM * 4);

  rms_slow<<<ROWS, 64, 0, stream>>>(x, gamma, xn);
  gemm_nn<float><<<dim3(ROWS / 128, NQKV / 128), 256, 0, stream>>>(xn, wq, qkvf, ROWS, NQKV, DIM);
  kvout_slow<<<65536, 256, 0, stream>>>(qkvf, cached);
  rope_slow<<<32768, 256, 0, stream>>>(qkvf);
  transpose_v_cast<<<dim3(DH / 32, SEQ / 32, 32), dim3(32, 8), 0, stream>>>(qkvf, vT);
  pack_qk<<<ROWS, 256, 0, stream>>>(qkvf);
  attn_mfma16<<<dim3(128, 32), 64, 0, stream>>>((const u16*)qkvf, vT, ctx);
  gemm_nn<u16><<<dim3(ROWS / 128, DIM / 128), 256, 0, stream>>>(ctx, wo, out, ROWS, DIM, DIM);
}

// Round 9
// 799.658 us; speedup vs baseline: 16.2529x; 1.0001x over previous
//
#include <hip/hip_runtime.h>
#include <cstdint>
#include <cstddef>
#include <math.h>

#define SEQ   2048
#define DIM   2048
#define NQKV  6144
#define NH    16
#define DH    128
#define ROWS  4096   /* b*n */

typedef unsigned short u16;
typedef unsigned int u32;
typedef __attribute__((ext_vector_type(8))) short bf16x8;
typedef __attribute__((ext_vector_type(4))) float f32x4;

__device__ __forceinline__ u16 f2bf(float f) {
  union { float f; u32 u; } v;
  v.f = f;
  u32 r = v.u + 0x7FFFu + ((v.u >> 16) & 1u);
  return (u16)(r >> 16);
}

// ------------------------------------------------ rmsnorm (fp64, 1 wave/row)
// [VERIFIED round 4 — do not touch]
__global__ __launch_bounds__(64) void rms_slow(
    const float* __restrict__ x, const float* __restrict__ g,
    float* __restrict__ xn) {
  int row = blockIdx.x, lane = threadIdx.x;
  const float* xr = x + (size_t)row * DIM;
  double ss = 0.0;
  for (int c = lane; c < DIM; c += 64) { double v = xr[c]; ss += v * v; }
  #pragma unroll
  for (int off = 32; off >= 1; off >>= 1) ss += __shfl_xor(ss, off);
  double nrm = sqrt(ss); if (nrm < 1e-12) nrm = 1e-12;
  double sc = 45.254833995939045 / nrm;   // sqrt(2048)/||x||
  float* dst = xn + (size_t)row * DIM;
  for (int c = lane; c < DIM; c += 64) dst[c] = (float)((double)xr[c] * sc * (double)g[c]);
}

// ------------------------- bf16 MFMA NN GEMM, A fp32-cast or native bf16 ----
// [VERIFIED rounds 5/6 — unchanged]
template <typename AT>
__global__ __launch_bounds__(256) void gemm_nn(
    const AT* __restrict__ A, const float* __restrict__ B,
    float* __restrict__ C, int M, int N, int K) {
  __shared__ u16 As[128 * 40];   // [m][k]
  __shared__ u16 Bs[128 * 40];   // [n][k]
  int bm = blockIdx.x * 128;
  int bn = blockIdx.y * 128;
  int tid = threadIdx.x;
  int wid = tid >> 6, lane = tid & 63;
  int wr = wid >> 1, wc = wid & 1;
  int fr = lane & 15, fq = lane >> 4;

  int ar = tid >> 1;
  int ak = (tid & 1) * 16;
  int bn_t = tid & 127;
  int bk_t = tid >> 7;

  f32x4 acc[4][4] = {};

  const u16* a_rd = As + (wr * 64 + fr) * 40 + fq * 8;
  const u16* b_rd = Bs + (wc * 64 + fr) * 40 + fq * 8;

  for (int k0 = 0; k0 < K; k0 += 32) {
    int4 aq0, aq1;
    if constexpr (sizeof(AT) == 4) {
      const float4* ap = (const float4*)(A + (size_t)(bm + ar) * K + k0 + ak);
      float4 a0 = ap[0], a1 = ap[1], a2 = ap[2], a3 = ap[3];
      union { u16 h[16]; int4 q[2]; } cv;
      cv.h[0]=f2bf(a0.x); cv.h[1]=f2bf(a0.y); cv.h[2]=f2bf(a0.z); cv.h[3]=f2bf(a0.w);
      cv.h[4]=f2bf(a1.x); cv.h[5]=f2bf(a1.y); cv.h[6]=f2bf(a1.z); cv.h[7]=f2bf(a1.w);
      cv.h[8]=f2bf(a2.x); cv.h[9]=f2bf(a2.y); cv.h[10]=f2bf(a2.z); cv.h[11]=f2bf(a2.w);
      cv.h[12]=f2bf(a3.x); cv.h[13]=f2bf(a3.y); cv.h[14]=f2bf(a3.z); cv.h[15]=f2bf(a3.w);
      aq0 = cv.q[0]; aq1 = cv.q[1];
    } else {
      const int4* ap = (const int4*)(A + (size_t)(bm + ar) * K + k0 + ak);
      aq0 = ap[0]; aq1 = ap[1];
    }
    float breg[16];
    #pragma unroll
    for (int it = 0; it < 16; ++it)
      breg[it] = B[(size_t)(k0 + bk_t + it * 2) * N + bn + bn_t];

    __syncthreads();
    *(int4*)(As + ar * 40 + ak) = aq0;
    *(int4*)(As + ar * 40 + ak + 8) = aq1;
    #pragma unroll
    for (int it = 0; it < 16; ++it)
      Bs[bn_t * 40 + bk_t + it * 2] = f2bf(breg[it]);
    __syncthreads();

    bf16x8 af[4], bfr[4];
    #pragma unroll
    for (int m = 0; m < 4; ++m) af[m]  = *(const bf16x8*)(a_rd + m * 16 * 40);
    #pragma unroll
    for (int n = 0; n < 4; ++n) bfr[n] = *(const bf16x8*)(b_rd + n * 16 * 40);
    #pragma unroll
    for (int m = 0; m < 4; ++m)
      #pragma unroll
      for (int n = 0; n < 4; ++n)
        acc[m][n] = __builtin_amdgcn_mfma_f32_16x16x32_bf16(af[m], bfr[n], acc[m][n], 0, 0, 0);
  }
  #pragma unroll
  for (int m = 0; m < 4; ++m)
    #pragma unroll
    for (int n = 0; n < 4; ++n)
      #pragma unroll
      for (int r = 0; r < 4; ++r) {
        int row = bm + wr * 64 + m * 16 + fq * 4 + r;
        int col = bn + wc * 64 + n * 16 + fr;
        C[(size_t)row * N + col] = acc[m][n][r];
      }
}

// ---------------------------------- cached_kv: one thread per output element
// [VERIFIED round 4 — do not touch]
__global__ __launch_bounds__(256) void kvout_slow(
    const float* __restrict__ qkv, float* __restrict__ cached) {
  size_t gid = (size_t)blockIdx.x * 256 + threadIdx.x;  // 16,777,216
  int d = (int)(gid & 127);
  size_t r = gid >> 7;
  int n = (int)(r & 2047); r >>= 11;
  int h = (int)(r & 15);   r >>= 4;
  int b = (int)(r & 1);    r >>= 1;
  int kv = (int)r;         // 0=k, 1=v  (pre-RoPE)
  cached[gid] = qkv[(size_t)(b * SEQ + n) * NQKV + (size_t)(1 + kv) * DIM + h * DH + d];
}

// ------------------------------------------- RoPE in-place (fp64, per pair)
// [VERIFIED round 4 — do not touch]
__global__ __launch_bounds__(256) void rope_slow(float* __restrict__ qkv) {
  int gid = blockIdx.x * 256 + threadIdx.x;   // 8,388,608 pairs (q and k)
  int p = gid & 63;
  int n = (gid >> 6) & 2047;
  int h = (gid >> 17) & 15;
  int s = (gid >> 21) & 1;    // 0 = q, 1 = k
  int b = (gid >> 22) & 1;
  float* base = qkv + (size_t)(b * SEQ + n) * NQKV + s * DIM + h * DH + 2 * p;
  double inv = pow(10000.0, -(double)p / 64.0);  // 10000^(-2p/128)
  double ang = (double)n * inv;
  double cs = cos(ang), sn = sin(ang);
  double t0 = base[0], t1 = base[1];
  base[0] = (float)(t0 * cs - t1 * sn);
  base[1] = (float)(t1 * cs + t0 * sn);
}

// ------------------------- V transpose + cast -> vT[bh][d][n] (bf16) --------
// [VERIFIED round 6 — unchanged]
__global__ void transpose_v_cast(const float* __restrict__ qkv,
                                 u16* __restrict__ vT) {
  int bh = blockIdx.z; int b = bh >> 4, h = bh & 15;
  int d0 = blockIdx.x * 32, n0 = blockIdx.y * 32;
  __shared__ float tile[32][33];
  int tx = threadIdx.x, ty = threadIdx.y;   // (32,8)
  const float* src = qkv + (size_t)(b * SEQ + n0) * NQKV + 2 * DIM + h * DH + d0;
  #pragma unroll
  for (int j = 0; j < 32; j += 8)
    tile[ty + j][tx] = src[(size_t)(ty + j) * NQKV + tx];
  __syncthreads();
  u16* dst = vT + ((size_t)bh * DH + d0) * SEQ + n0;
  #pragma unroll
  for (int j = 0; j < 32; j += 8)
    dst[(size_t)(ty + j) * SEQ + tx] = f2bf(tile[tx][ty + j]);
}

// ----------------- pack post-RoPE q,k as bf16 into the dead fp32-V region ---
// [VERIFIED round 7 — unchanged]
__global__ __launch_bounds__(256) void pack_qk(float* __restrict__ qkv) {
  int row = blockIdx.x;           // 0..4095
  int t = threadIdx.x;            // 16 elems each over q+k (4096 elems)
  const float* src = qkv + (size_t)row * NQKV + t * 16;
  float4 f0 = ((const float4*)src)[0];
  float4 f1 = ((const float4*)src)[1];
  float4 f2 = ((const float4*)src)[2];
  float4 f3 = ((const float4*)src)[3];
  union { u16 h[16]; int4 q[2]; } cv;
  cv.h[0]=f2bf(f0.x);  cv.h[1]=f2bf(f0.y);  cv.h[2]=f2bf(f0.z);  cv.h[3]=f2bf(f0.w);
  cv.h[4]=f2bf(f1.x);  cv.h[5]=f2bf(f1.y);  cv.h[6]=f2bf(f1.z);  cv.h[7]=f2bf(f1.w);
  cv.h[8]=f2bf(f2.x);  cv.h[9]=f2bf(f2.y);  cv.h[10]=f2bf(f2.z); cv.h[11]=f2bf(f2.w);
  cv.h[12]=f2bf(f3.x); cv.h[13]=f2bf(f3.y); cv.h[14]=f2bf(f3.z); cv.h[15]=f2bf(f3.w);
  u16* dst = (u16*)(qkv + (size_t)row * NQKV) + 8192 + t * 16;
  ((int4*)dst)[0] = cv.q[0];
  ((int4*)dst)[1] = cv.q[1];
}

// --------------------- MFMA causal flash attention, 1 wave / 16 q-rows ------
// Round-7 kernel + in-register pipelining: K tile prefetched one tile ahead
// into the same registers (dead after QK), V loads hoisted above softmax.
// Tile math (QK/mask/softmax/P-LDS/PV/epilogue) byte-identical to round 7.
__global__ __launch_bounds__(64) void attn_mfma16(
    const u16* __restrict__ qkp,   // u16 view of qkvf (packed q,k in V region)
    const u16* __restrict__ vT,    // (32,128,2048) bf16
    u16* __restrict__ ctx) {       // (4096, 2048) bf16
  int qt = 127 - blockIdx.x;       // longest blocks first
  int bh = blockIdx.y;             // 0..31
  int b = bh >> 4, h = bh & 15;
  int lane = threadIdx.x;
  int fr = lane & 15, fq = lane >> 4;
  int qr0 = qt * 16;

  __shared__ u16 Pw[16 * 72];

  const size_t rstr = 2 * NQKV;    // u16 per row
  const u16* Qb = qkp + (size_t)(b * SEQ) * rstr + 8192 + h * 128;
  const u16* Kb = qkp + (size_t)(b * SEQ) * rstr + 10240 + h * 128;
  const u16* Vt = vT + (size_t)bh * DH * SEQ;

  bf16x8 qf[4];
  {
    const u16* qrow = Qb + (size_t)(qr0 + fr) * rstr + fq * 8;
    #pragma unroll
    for (int kk = 0; kk < 4; ++kk) qf[kk] = *(const bf16x8*)(qrow + kk * 32);
  }

  f32x4 acc[8] = {};
  float m_r[4], l_r[4];
  #pragma unroll
  for (int r = 0; r < 4; ++r) { m_r[r] = -3e38f; l_r[r] = 0.f; }

  const float scale = 0.08838834764831845f;
  int i0 = qr0 + fq * 4;
  int jt_end = qt >> 2;

  // register-resident K and V tiles
  bf16x8 kreg[16];   // [jf][kk]
  bf16x8 vreg[16];   // [df][half]

  // preload K tile 0
  #pragma unroll
  for (int jf = 0; jf < 4; ++jf) {
    const u16* krow = Kb + (size_t)(jf * 16 + fr) * rstr + fq * 8;
    #pragma unroll
    for (int kk = 0; kk < 4; ++kk) kreg[jf * 4 + kk] = *(const bf16x8*)(krow + kk * 32);
  }

  for (int jt = 0; jt <= jt_end; ++jt) {
    int j0 = jt * 64;

    // issue V loads for THIS tile now — consumed after softmax (~1k cy later)
    #pragma unroll
    for (int df = 0; df < 8; ++df) {
      const u16* vrow = Vt + (size_t)(df * 16 + fr) * SEQ + j0 + fq * 8;
      vreg[df * 2]     = *(const bf16x8*)(vrow);
      vreg[df * 2 + 1] = *(const bf16x8*)(vrow + 32);
    }

    // QK^T from register-resident K
    f32x4 s[4];
    #pragma unroll
    for (int jf = 0; jf < 4; ++jf) {
      f32x4 sa = {0.f, 0.f, 0.f, 0.f};
      #pragma unroll
      for (int kk = 0; kk < 4; ++kk)
        sa = __builtin_amdgcn_mfma_f32_16x16x32_bf16(qf[kk], kreg[jf * 4 + kk], sa, 0, 0, 0);
      s[jf] = sa;
    }

    // prefetch NEXT K tile into the same (now dead) registers;
    // refill latency hides under mask+softmax+P below.
    if (jt < jt_end) {
      int jn0 = j0 + 64;
      #pragma unroll
      for (int jf = 0; jf < 4; ++jf) {
        const u16* krow = Kb + (size_t)(jn0 + jf * 16 + fr) * rstr + fq * 8;
        #pragma unroll
        for (int kk = 0; kk < 4; ++kk) kreg[jf * 4 + kk] = *(const bf16x8*)(krow + kk * 32);
      }
    }

    #pragma unroll
    for (int jf = 0; jf < 4; ++jf) {
      int j = j0 + jf * 16 + fr;
      #pragma unroll
      for (int r = 0; r < 4; ++r) {
        float v = s[jf][r] * scale;
        s[jf][r] = (j > i0 + r) ? -1e30f : v;
      }
    }
    float al[4], ls[4];
    #pragma unroll
    for (int r = 0; r < 4; ++r) {
      float mx = fmaxf(fmaxf(s[0][r], s[1][r]), fmaxf(s[2][r], s[3][r]));
      #pragma unroll
      for (int off = 8; off >= 1; off >>= 1) mx = fmaxf(mx, __shfl_xor(mx, off));
      float mn = fmaxf(m_r[r], mx);
      al[r] = __expf(m_r[r] - mn);
      m_r[r] = mn;
      float sum = 0.f;
      #pragma unroll
      for (int jf = 0; jf < 4; ++jf) {
        float p = __expf(s[jf][r] - mn);
        s[jf][r] = p;
        sum += p;
      }
      #pragma unroll
      for (int off = 8; off >= 1; off >>= 1) sum += __shfl_xor(sum, off);
      ls[r] = sum;
    }
    #pragma unroll
    for (int jf = 0; jf < 4; ++jf)
      #pragma unroll
      for (int r = 0; r < 4; ++r)
        Pw[(fq * 4 + r) * 72 + jf * 16 + fr] = f2bf(s[jf][r]);
    #pragma unroll
    for (int r = 0; r < 4; ++r) l_r[r] = l_r[r] * al[r] + ls[r];
    #pragma unroll
    for (int df = 0; df < 8; ++df)
      #pragma unroll
      for (int r = 0; r < 4; ++r) acc[df][r] *= al[r];

    bf16x8 pa0 = *(const bf16x8*)(Pw + fr * 72 + fq * 8);
    bf16x8 pa1 = *(const bf16x8*)(Pw + fr * 72 + 32 + fq * 8);
    #pragma unroll
    for (int df = 0; df < 8; ++df) {
      acc[df] = __builtin_amdgcn_mfma_f32_16x16x32_bf16(pa0, vreg[df * 2],     acc[df], 0, 0, 0);
      acc[df] = __builtin_amdgcn_mfma_f32_16x16x32_bf16(pa1, vreg[df * 2 + 1], acc[df], 0, 0, 0);
    }
  }
  #pragma unroll
  for (int df = 0; df < 8; ++df)
    #pragma unroll
    for (int r = 0; r < 4; ++r) {
      int i = qr0 + fq * 4 + r;
      int d = df * 16 + fr;
      ctx[(size_t)(b * SEQ + i) * DIM + h * DH + d] = f2bf(acc[df][r] / l_r[r]);
    }
}

// ----------------------------------------------------------------- launch ---
extern "C" void kernel_launch(void* const* d_in, const int* in_sizes, int n_in,
                              void* d_out, int out_size, void* d_ws, size_t ws_size,
                              hipStream_t stream) {
  // size-keyed input selection (sizes are pairwise distinct)
  const float *x = nullptr, *gamma = nullptr, *wq = nullptr, *wo = nullptr;
  for (int ii = 0; ii < n_in; ++ii) {
    switch (in_sizes[ii]) {
      case  8388608: x     = (const float*)d_in[ii]; break;
      case     2048: gamma = (const float*)d_in[ii]; break;
      case 12582912: wq    = (const float*)d_in[ii]; break;
      case  4194304: wo    = (const float*)d_in[ii]; break;
    }
  }
  if (!x || !gamma || !wq || !wo) {   // fallback: documented dict order
    x = (const float*)d_in[0]; gamma = (const float*)d_in[1];
    wq = (const float*)d_in[2]; wo = (const float*)d_in[3];
  }

  float* out    = (float*)d_out;           // (2,2048,2048)
  float* cached = out + 8388608;           // (2,2,16,2048,128)

  // ws (134.2 MB, proven footprint):
  //   [0, 33.55MB)      xn (fp32) — dead after QKV GEMM; then reused as:
  //       [0, 16.78MB)      ctx (bf16)
  //       [16.78, 33.55MB)  vT  (bf16)
  //   [33.55, 134.2MB)  qkv (fp32; V third repurposed for packed bf16 q,k)
  float* xn   = (float*)d_ws;
  u16*   ctx  = (u16*)d_ws;
  u16*   vT   = ctx + (size_t)ROWS * DIM;
  float* qkvf = (float*)((char*)d_ws + (size_t)ROWS * DIM * 4);

  rms_slow<<<ROWS, 64, 0, stream>>>(x, gamma, xn);
  gemm_nn<float><<<dim3(ROWS / 128, NQKV / 128), 256, 0, stream>>>(xn, wq, qkvf, ROWS, NQKV, DIM);
  kvout_slow<<<65536, 256, 0, stream>>>(qkvf, cached);
  rope_slow<<<32768, 256, 0, stream>>>(qkvf);
  transpose_v_cast<<<dim3(DH / 32, SEQ / 32, 32), dim3(32, 8), 0, stream>>>(qkvf, vT);
  pack_qk<<<ROWS, 256, 0, stream>>>(qkvf);
  attn_mfma16<<<dim3(128, 32), 64, 0, stream>>>((const u16*)qkvf, vT, ctx);
  gemm_nn<u16><<<dim3(ROWS / 128, DIM / 128), 256, 0, stream>>>(ctx, wo, out, ROWS, DIM, DIM);
}